// Round 5
// baseline (282.788 us; speedup 1.0000x reference)
//
#include <hip/hip_runtime.h>
#include <stdint.h>

// Problem constants (SparseMPNN_30709016166923): B=2, N=40000, E=640000, H=4, F=32
#define BB     2
#define NNODE  40000
#define NEDGE  640000
#define NH     4
#define NF     32
#define NHF    128   // NH*NF
#define SEGN   (BB * NNODE)          // 80000 segments (b,node)
#define GEDGE  (BB * NEDGE)          // 1,280,000 global edges
#define SLOT   48                    // per-node bucket capacity (deg~Poisson(16))

// two-phase binning
#define W      512                   // nodes per coarse bucket (pow2)
#define NBK_B  79                    // ceil(40000/512) buckets per batch
#define NBK    (BB * NBK_B)          // 158 coarse buckets
#define CAP    9216                  // pairs per coarse bucket (mean 8192, +11 sigma)
#define BLK_E  2048                  // edges per binA block
#define NBLKA  (GEDGE / BLK_E)       // 625 (exact)

static constexpr float NEG_SLOPE = 0.2f;
static constexpr float NEG_BIG   = -3.4e38f;

typedef float vf4 __attribute__((ext_vector_type(4)));   // native vector: nontemporal-store legal

// ---------- kernel 1: per-node attention logits + zero bucket cursors ----------
__global__ void prep_k(const float* __restrict__ X,
                       const float* __restrict__ As,
                       const float* __restrict__ Aa,
                       float* __restrict__ S, float* __restrict__ A,
                       unsigned* __restrict__ cursor) {
    int idx = blockIdx.x * blockDim.x + threadIdx.x;   // (b,n,h)
    if (idx < NBK) cursor[idx] = 0u;                   // fused cursor zero-init
    if (idx >= SEGN * NH) return;
    int h = idx & (NH - 1);
    const float4* xv = (const float4*)(X + (size_t)idx * NF);
    const float4* sv = (const float4*)(As + h * NF);
    const float4* av = (const float4*)(Aa + h * NF);
    float s = 0.f, a = 0.f;
#pragma unroll
    for (int i = 0; i < 8; ++i) {
        float4 x = xv[i];
        float4 ws = sv[i];
        float4 wa = av[i];
        s += x.x * ws.x + x.y * ws.y + x.z * ws.z + x.w * ws.w;
        a += x.x * wa.x + x.y * wa.y + x.z * wa.z + x.w * wa.w;
    }
    S[idx] = s;
    A[idx] = a;
}

// ---------- kernel 2 (bin phase A): coarse partition, LDS-sorted coalesced writes ----------
// R12: nontemporal loads (tg/sc read-once) and stores (pairs consumed cross-XCD
// via LLC anyway) — keep L2 free for gather's X rows.
__global__ __launch_bounds__(256) void binA_k(const int* __restrict__ tg,
                                              const int* __restrict__ sc,
                                              unsigned* __restrict__ cursor,
                                              unsigned* __restrict__ pairs) {
    __shared__ unsigned hist[NBK];
    __shared__ unsigned lofs[NBK];
    __shared__ unsigned gofs[NBK];
    __shared__ unsigned wsum[4];
    __shared__ unsigned staged[BLK_E];
    __shared__ unsigned char sbk[BLK_E];
    int t = threadIdx.x;
    int base = blockIdx.x * BLK_E;
    for (int i = t; i < NBK; i += 256) hist[i] = 0u;
    __syncthreads();

    unsigned pr[8];
    unsigned short pbk[8], plp[8];
#pragma unroll
    for (int k = 0; k < 8; ++k) {
        int e = base + k * 256 + t;                    // exact: 625*2048 == GEDGE
        int tgv = __builtin_nontemporal_load(tg + e);
        int scv = __builtin_nontemporal_load(sc + e);
        int b = (e >= NEDGE) ? 1 : 0;
        unsigned bk = (unsigned)(b * NBK_B + (tgv >> 9));
        pr[k]  = ((unsigned)(tgv & (W - 1)) << 16) | (unsigned)scv;  // src<40000 fits u16
        pbk[k] = (unsigned short)bk;
        plp[k] = (unsigned short)atomicAdd(&hist[bk], 1u);
    }
    __syncthreads();
    // parallel exclusive scan of hist[0..NBK) -> lofs
    {
        int lane = t & 63, w = t >> 6;
        unsigned v = (t < NBK) ? hist[t] : 0u;
        unsigned inc = v;
#pragma unroll
        for (int d = 1; d < 64; d <<= 1) {
            unsigned u = __shfl_up(inc, d);
            if (lane >= d) inc += u;
        }
        if (lane == 63) wsum[w] = inc;
        __syncthreads();
        unsigned woff = 0;
#pragma unroll
        for (int i = 0; i < 3; ++i) { if (i < w) woff += wsum[i]; }
        if (t < NBK) {
            lofs[t] = woff + inc - v;                  // exclusive prefix
            if (v > 0u)
                gofs[t] = atomicAdd(&cursor[t], v);    // one reserve per bucket
        }
    }
    __syncthreads();
#pragma unroll
    for (int k = 0; k < 8; ++k) {
        unsigned j = lofs[pbk[k]] + plp[k];
        staged[j] = pr[k];
        sbk[j] = (unsigned char)pbk[k];
    }
    __syncthreads();
    for (int j = t; j < BLK_E; j += 256) {
        unsigned bk = sbk[j];
        unsigned dst = gofs[bk] + ((unsigned)j - lofs[bk]);
        if (dst < CAP)                                  // 11-sigma guard
            __builtin_nontemporal_store(staged[j], pairs + (size_t)bk * CAP + dst);
    }
}

// ---------- kernel 3 (bin phase B): fine-bin one coarse bucket in LDS ----------
__global__ __launch_bounds__(1024) void binB_k(const unsigned* __restrict__ cursor,
                                               const unsigned* __restrict__ pairs,
                                               unsigned short* __restrict__ srt,
                                               unsigned* __restrict__ deg) {
    __shared__ unsigned short loc[W * SLOT];            // 49,152 B
    __shared__ unsigned dloc[W];
    int t = threadIdx.x;
    int gbk = blockIdx.x;                               // 0..157
    int b = gbk / NBK_B;
    int bkloc = gbk - b * NBK_B;
    int node0 = b * NNODE + bkloc * W;
    int wEff = min(W, NNODE - bkloc * W);               // 512 (or 64 for last bucket)
    for (int i = t; i < W; i += 1024) dloc[i] = 0u;
    __syncthreads();
    int nE = (int)min(cursor[gbk], (unsigned)CAP);
    const unsigned* pb = pairs + (size_t)gbk * CAP;
    for (int j = t; j < nE; j += 1024) {
        unsigned p = __builtin_nontemporal_load(pb + j);
        unsigned tl = p >> 16;                          // node local to bucket
        unsigned pos = atomicAdd(&dloc[tl], 1u);
        if (pos < SLOT)
            loc[tl * SLOT + pos] = (unsigned short)(p & 0xFFFFu);
    }
    __syncthreads();
    unsigned* srt32 = (unsigned*)(srt + (size_t)node0 * SLOT);  // 96B/node, 4B-aligned
    const unsigned* loc32 = (const unsigned*)loc;
    int n32 = wEff * SLOT / 2;
    for (int i = t; i < n32; i += 1024)
        __builtin_nontemporal_store(loc32[i], srt32 + i);       // full-line streams
    for (int i = t; i < wEff; i += 1024)
        __builtin_nontemporal_store(dloc[i], deg + node0 + i);
}

// ---------- kernel 4: gather — fully branchless, deep load pipelining ----------
// R12/R13: R3 showed VGPR_Count=16 — the 24 per-iteration wave-uniform guards
// forced the compiler into ~2-deep load batching (latency-serialized, VALUBusy
// 27%). This version is 100% branchless:
//  - staging: srt ALWAYS read (SLOT=48 entries allocated per node); garbage
//    slots (binB streams uninitialized LDS) clamped to NNODE-1 -> sb in
//    [0,SEGN), so A/X reads provably in-bounds; per-lane select gives them
//    v=NEG_BIG and w=0.
//  - accumulate: all 24 pair-iterations unconditional, fully unrolled, static
//    indices -> compiler can issue many independent dwordx4 loads ahead.
//  - padding loads all hit the same clamped row -> L1-resident, ~no FETCH.
// w=0 contributions are fp-exact no-ops (0*x + acc == acc), so results are
// bitwise identical to the guarded version (absmax 0.03125 preserved).
// Lane t owns f-quad q=t&31; halves h32=t>>5 take even/odd edges; merge via
// shfl_xor(32). 4 nodes (4 waves) per block. OUT stored nontemporally (never
// re-read; vf4 native vector — HIP float4 class is rejected by the builtin).
__global__ __launch_bounds__(256) void gather_k(
        const float* __restrict__ X, const float* __restrict__ S,
        const float* __restrict__ A, const unsigned* __restrict__ deg,
        const unsigned short* __restrict__ srt, float* __restrict__ OUT) {
    int node = blockIdx.x * 4 + (threadIdx.x >> 6);
    int t = threadIdx.x & 63;                   // lane 0..63
    int hs = t & 3;                             // staging head
    int es = t >> 2;                            // staging edge slot 0..15 within group
    int h32 = t >> 5;                           // which edge of the pair
    int q = t & 31;                             // f-quad index 0..31
    int haq = q >> 3;                           // accumulation head for quad
    int dg = min((int)__builtin_nontemporal_load(deg + node), SLOT);
    int bbase = (node >= NNODE) ? NNODE : 0;
    size_t beg = (size_t)node * SLOT;

    float sh = S[node * NH + hs];

    // branchless staging: 3 independent srt loads, clamp, 3 A gathers
    unsigned r0 = __builtin_nontemporal_load(srt + beg + es);
    unsigned r1 = __builtin_nontemporal_load(srt + beg + 16 + es);
    unsigned r2 = __builtin_nontemporal_load(srt + beg + 32 + es);
    int sb[3];
    sb[0] = bbase + (int)min(r0, NNODE - 1u);
    sb[1] = bbase + (int)min(r1, NNODE - 1u);
    sb[2] = bbase + (int)min(r2, NNODE - 1u);
    float v[3];
#pragma unroll
    for (int c = 0; c < 3; ++c) {
        float vv = sh + A[sb[c] * NH + hs];
        vv = vv > 0.f ? vv : NEG_SLOPE * vv;
        v[c] = (16 * c + es < dg) ? vv : NEG_BIG;   // garbage (maybe NaN) never enters max
    }
    // in-register segment max per head class (lanes ≡ hs mod 4)
    float m = fmaxf(fmaxf(v[0], v[1]), v[2]);
    m = fmaxf(m, __shfl_xor(m, 4));
    m = fmaxf(m, __shfl_xor(m, 8));
    m = fmaxf(m, __shfl_xor(m, 16));
    m = fmaxf(m, __shfl_xor(m, 32));
    float w[3];
#pragma unroll
    for (int c = 0; c < 3; ++c)
        w[c] = (16 * c + es < dg) ? __expf(v[c] - m) : 0.f;  // dg==0 -> all w 0

    vf4 acc = (vf4)(0.f);
#pragma unroll
    for (int i = 0; i < 24; ++i) {              // unconditional; i>>3 static after unroll
        int e2 = 2 * i + h32;
        float we  = __shfl(w[i >> 3],  4 * (e2 & 15) + haq);
        int   sbe = __shfl(sb[i >> 3], 4 * (e2 & 15));
        const vf4 x = *(const vf4*)(X + (size_t)sbe * NHF + 4 * q);
        acc += x * we;
    }
    // merge even/odd-edge halves (identical scaling: both use m1)
    acc.x += __shfl_xor(acc.x, 32);
    acc.y += __shfl_xor(acc.y, 32);
    acc.z += __shfl_xor(acc.z, 32);
    acc.w += __shfl_xor(acc.w, 32);
    if (t < 32) {
        __builtin_nontemporal_store(acc, (vf4*)(OUT + (size_t)node * NHF + 4 * q));
    }
}

extern "C" void kernel_launch(void* const* d_in, const int* in_sizes, int n_in,
                              void* d_out, int out_size, void* d_ws, size_t ws_size,
                              hipStream_t stream) {
    const float* X  = (const float*)d_in[0];
    const float* As = (const float*)d_in[1];
    const float* Aa = (const float*)d_in[2];
    const int* tg = (const int*)d_in[4];
    const int* sc = (const int*)d_in[5];
    float* OUT = (float*)d_out;

    // Workspace layout, total 16,385,152 B (proven safe: R7 ran with ws_size
    // >= 18,240,000; R1 proved ~24.3MB overflows and corrupts harness state):
    //   S      @ 0          : 1,280,000  (SEGN*NH fp32)
    //   A      @ 1,280,000  : 1,280,000
    //   deg    @ 2,560,000  :   320,000  (SEGN u32)
    //   cursor @ 2,880,000  :       640  (NBK u32, padded)
    //   pairs  @ 2,880,640  : 5,824,512  (NBK*CAP u32)
    //   srt    @ 8,705,152  : 7,680,000  (SEGN*SLOT u16)
    char* ws = (char*)d_ws;
    float*          S      = (float*)ws;
    float*          A      = (float*)(ws + 1280000);
    unsigned*       deg    = (unsigned*)(ws + 2560000);
    unsigned*       cursor = (unsigned*)(ws + 2880000);
    unsigned*       pairs  = (unsigned*)(ws + 2880640);
    unsigned short* srt    = (unsigned short*)(ws + 8705152);

    const int nlog = SEGN * NH;                  // 320,000
    prep_k<<<(nlog + 255) / 256, 256, 0, stream>>>(X, As, Aa, S, A, cursor);
    binA_k<<<NBLKA, 256, 0, stream>>>(tg, sc, cursor, pairs);
    binB_k<<<NBK, 1024, 0, stream>>>(cursor, pairs, srt, deg);
    gather_k<<<SEGN / 4, 256, 0, stream>>>(X, S, A, deg, srt, OUT);
}

// Round 6
// 233.278 us; speedup vs baseline: 1.2122x; 1.2122x over previous
//
#include <hip/hip_runtime.h>
#include <stdint.h>

// Problem constants (SparseMPNN_30709016166923): B=2, N=40000, E=640000, H=4, F=32
#define BB     2
#define NNODE  40000
#define NEDGE  640000
#define NH     4
#define NF     32
#define NHF    128   // NH*NF
#define SEGN   (BB * NNODE)          // 80000 segments (b,node)
#define GEDGE  (BB * NEDGE)          // 1,280,000 global edges
#define SLOT   48                    // per-node bucket capacity (deg~Poisson(16))

// two-phase binning
#define W      512                   // nodes per coarse bucket (pow2)
#define NBK_B  79                    // ceil(40000/512) buckets per batch
#define NBK    (BB * NBK_B)          // 158 coarse buckets
#define CAP    9216                  // pairs per coarse bucket (mean 8192, +11 sigma)
#define BLK_E  2048                  // edges per binA block
#define NBLKA  (GEDGE / BLK_E)       // 625 (exact; 625*512 == 320000 logit rows too)

static constexpr float NEG_SLOPE = 0.2f;
static constexpr float NEG_BIG   = -3.4e38f;

typedef float vf4 __attribute__((ext_vector_type(4)));   // native vector: nontemporal-store legal

// ---------- kernel 1 (fused): coarse partition + per-node logits ----------
// R14: prep_k fused into binA_k — the logit dot-products (X streaming, FMA)
// fill the latency bubbles of the edge phase's LDS atomics, and one dispatch
// is removed. 625 blocks x 512 logit rows == 320,000 exact. cursor zero-init
// moved to hipMemsetAsync on the stream (graph-capturable).
__global__ __launch_bounds__(256) void binA_k(const int* __restrict__ tg,
                                              const int* __restrict__ sc,
                                              const float* __restrict__ X,
                                              const float* __restrict__ As,
                                              const float* __restrict__ Aa,
                                              float* __restrict__ S,
                                              float* __restrict__ A,
                                              unsigned* __restrict__ cursor,
                                              unsigned* __restrict__ pairs) {
    __shared__ unsigned hist[NBK];
    __shared__ unsigned lofs[NBK];
    __shared__ unsigned gofs[NBK];
    __shared__ unsigned wsum[4];
    __shared__ unsigned staged[BLK_E];
    __shared__ unsigned char sbk[BLK_E];
    int t = threadIdx.x;
    int base = blockIdx.x * BLK_E;
    for (int i = t; i < NBK; i += 256) hist[i] = 0u;
    __syncthreads();

    unsigned pr[8];
    unsigned short pbk[8], plp[8];
#pragma unroll
    for (int k = 0; k < 8; ++k) {
        int e = base + k * 256 + t;                    // exact: 625*2048 == GEDGE
        int tgv = __builtin_nontemporal_load(tg + e);
        int scv = __builtin_nontemporal_load(sc + e);
        int b = (e >= NEDGE) ? 1 : 0;
        unsigned bk = (unsigned)(b * NBK_B + (tgv >> 9));
        pr[k]  = ((unsigned)(tgv & (W - 1)) << 16) | (unsigned)scv;  // src<40000 fits u16
        pbk[k] = (unsigned short)bk;
        plp[k] = (unsigned short)atomicAdd(&hist[bk], 1u);
    }
    // fused prep: 2 logit rows per thread (fills atomic-latency bubbles)
#pragma unroll
    for (int r = 0; r < 2; ++r) {
        int idx = blockIdx.x * 512 + r * 256 + t;      // (b,n,h) row, < 320000
        int h = idx & (NH - 1);
        const float4* xv = (const float4*)(X + (size_t)idx * NF);
        const float4* sv = (const float4*)(As + h * NF);
        const float4* av = (const float4*)(Aa + h * NF);
        float s = 0.f, a = 0.f;
#pragma unroll
        for (int i = 0; i < 8; ++i) {
            float4 x = xv[i];
            float4 ws = sv[i];
            float4 wa = av[i];
            s += x.x * ws.x + x.y * ws.y + x.z * ws.z + x.w * ws.w;
            a += x.x * wa.x + x.y * wa.y + x.z * wa.z + x.w * wa.w;
        }
        S[idx] = s;
        A[idx] = a;
    }
    __syncthreads();
    // parallel exclusive scan of hist[0..NBK) -> lofs
    {
        int lane = t & 63, w = t >> 6;
        unsigned v = (t < NBK) ? hist[t] : 0u;
        unsigned inc = v;
#pragma unroll
        for (int d = 1; d < 64; d <<= 1) {
            unsigned u = __shfl_up(inc, d);
            if (lane >= d) inc += u;
        }
        if (lane == 63) wsum[w] = inc;
        __syncthreads();
        unsigned woff = 0;
#pragma unroll
        for (int i = 0; i < 3; ++i) { if (i < w) woff += wsum[i]; }
        if (t < NBK) {
            lofs[t] = woff + inc - v;                  // exclusive prefix
            if (v > 0u)
                gofs[t] = atomicAdd(&cursor[t], v);    // one reserve per bucket
        }
    }
    __syncthreads();
#pragma unroll
    for (int k = 0; k < 8; ++k) {
        unsigned j = lofs[pbk[k]] + plp[k];
        staged[j] = pr[k];
        sbk[j] = (unsigned char)pbk[k];
    }
    __syncthreads();
    for (int j = t; j < BLK_E; j += 256) {
        unsigned bk = sbk[j];
        unsigned dst = gofs[bk] + ((unsigned)j - lofs[bk]);
        if (dst < CAP)                                  // 11-sigma guard
            __builtin_nontemporal_store(staged[j], pairs + (size_t)bk * CAP + dst);
    }
}

// ---------- kernel 2 (bin phase B): fine-bin one coarse bucket in LDS ----------
__global__ __launch_bounds__(1024) void binB_k(const unsigned* __restrict__ cursor,
                                               const unsigned* __restrict__ pairs,
                                               unsigned short* __restrict__ srt,
                                               unsigned* __restrict__ deg) {
    __shared__ unsigned short loc[W * SLOT];            // 49,152 B
    __shared__ unsigned dloc[W];
    int t = threadIdx.x;
    int gbk = blockIdx.x;                               // 0..157
    int b = gbk / NBK_B;
    int bkloc = gbk - b * NBK_B;
    int node0 = b * NNODE + bkloc * W;
    int wEff = min(W, NNODE - bkloc * W);               // 512 (or 64 for last bucket)
    for (int i = t; i < W; i += 1024) dloc[i] = 0u;
    __syncthreads();
    int nE = (int)min(cursor[gbk], (unsigned)CAP);
    const unsigned* pb = pairs + (size_t)gbk * CAP;
    for (int j = t; j < nE; j += 1024) {
        unsigned p = __builtin_nontemporal_load(pb + j);
        unsigned tl = p >> 16;                          // node local to bucket
        unsigned pos = atomicAdd(&dloc[tl], 1u);
        if (pos < SLOT)
            loc[tl * SLOT + pos] = (unsigned short)(p & 0xFFFFu);
    }
    __syncthreads();
    unsigned* srt32 = (unsigned*)(srt + (size_t)node0 * SLOT);  // 96B/node, 4B-aligned
    const unsigned* loc32 = (const unsigned*)loc;
    int n32 = wEff * SLOT / 2;
    for (int i = t; i < n32; i += 1024)
        __builtin_nontemporal_store(loc32[i], srt32 + i);       // full-line streams
    for (int i = t; i < wEff; i += 1024)
        __builtin_nontemporal_store(dloc[i], deg + node0 + i);
}

// ---------- kernel 3: gather — branchless, padding redirected to edge-0 row ----------
// R14: R5 proved gather is FETCH-byte-bound (dur = 10us + FETCH/3.69TB/s): the
// branchless pipeline ran at identical bytes/s but fetched 523MB because
// garbage srt slots are arbitrary u16 < 40000 (clamp almost never fires) ->
// real random gathers. Fix: redirect all invalid slots to EDGE 0's source row
// (wave-broadcast via shfl). The wave fetches that row anyway -> padding loads
// are L1-hits, zero extra FETCH. w=0 keeps them fp-exact no-ops, so output is
// bit-identical to the guarded R3 version (absmax 0.03125 preserved).
// Lane t owns f-quad q=t&31; halves h32=t>>5 take even/odd edges; merge via
// shfl_xor(32). 4 nodes (4 waves) per block. All single-use streams (srt, deg,
// OUT) nontemporal to keep L2 for X rows.
__global__ __launch_bounds__(256) void gather_k(
        const float* __restrict__ X, const float* __restrict__ S,
        const float* __restrict__ A, const unsigned* __restrict__ deg,
        const unsigned short* __restrict__ srt, float* __restrict__ OUT) {
    int node = blockIdx.x * 4 + (threadIdx.x >> 6);
    int t = threadIdx.x & 63;                   // lane 0..63
    int hs = t & 3;                             // staging head
    int es = t >> 2;                            // staging edge slot 0..15 within group
    int h32 = t >> 5;                           // which edge of the pair
    int q = t & 31;                             // f-quad index 0..31
    int haq = q >> 3;                           // accumulation head for quad
    int dg = min((int)__builtin_nontemporal_load(deg + node), SLOT);
    int bbase = (node >= NNODE) ? NNODE : 0;
    size_t beg = (size_t)node * SLOT;

    float sh = S[node * NH + hs];

    // branchless staging: 3 independent srt loads, clamp, redirect pads to edge 0
    unsigned r0 = __builtin_nontemporal_load(srt + beg + es);
    unsigned r1 = __builtin_nontemporal_load(srt + beg + 16 + es);
    unsigned r2 = __builtin_nontemporal_load(srt + beg + 32 + es);
    int sbr0 = bbase + (int)min(r0, NNODE - 1u);
    int sbr1 = bbase + (int)min(r1, NNODE - 1u);
    int sbr2 = bbase + (int)min(r2, NNODE - 1u);
    int sbE0 = __shfl(sbr0, 0);                 // edge 0's row: fetched by wave anyway
    int sb[3];
    sb[0] = (es < dg)      ? sbr0 : sbE0;       // es==0 always valid when dg>0;
    sb[1] = (16 + es < dg) ? sbr1 : sbE0;       //  dg==0 -> all lanes sbE0 (1 row, w=0)
    sb[2] = (32 + es < dg) ? sbr2 : sbE0;
    float v[3];
#pragma unroll
    for (int c = 0; c < 3; ++c) {
        float vv = sh + A[sb[c] * NH + hs];     // pads read edge-0 row: L1-hot
        vv = vv > 0.f ? vv : NEG_SLOPE * vv;
        v[c] = (16 * c + es < dg) ? vv : NEG_BIG;
    }
    // in-register segment max per head class (lanes ≡ hs mod 4)
    float m = fmaxf(fmaxf(v[0], v[1]), v[2]);
    m = fmaxf(m, __shfl_xor(m, 4));
    m = fmaxf(m, __shfl_xor(m, 8));
    m = fmaxf(m, __shfl_xor(m, 16));
    m = fmaxf(m, __shfl_xor(m, 32));
    float w[3];
#pragma unroll
    for (int c = 0; c < 3; ++c)
        w[c] = (16 * c + es < dg) ? __expf(v[c] - m) : 0.f;  // pads: w = 0 exactly

    vf4 acc = (vf4)(0.f);
#pragma unroll
    for (int i = 0; i < 24; ++i) {              // unconditional; i>>3 static after unroll
        int e2 = 2 * i + h32;
        float we  = __shfl(w[i >> 3],  4 * (e2 & 15) + haq);
        int   sbe = __shfl(sb[i >> 3], 4 * (e2 & 15));
        const vf4 x = *(const vf4*)(X + (size_t)sbe * NHF + 4 * q);
        acc += x * we;                          // pad pairs: same row again -> L1 hit
    }
    // merge even/odd-edge halves (identical scaling: both use m1)
    acc.x += __shfl_xor(acc.x, 32);
    acc.y += __shfl_xor(acc.y, 32);
    acc.z += __shfl_xor(acc.z, 32);
    acc.w += __shfl_xor(acc.w, 32);
    if (t < 32) {
        __builtin_nontemporal_store(acc, (vf4*)(OUT + (size_t)node * NHF + 4 * q));
    }
}

extern "C" void kernel_launch(void* const* d_in, const int* in_sizes, int n_in,
                              void* d_out, int out_size, void* d_ws, size_t ws_size,
                              hipStream_t stream) {
    const float* X  = (const float*)d_in[0];
    const float* As = (const float*)d_in[1];
    const float* Aa = (const float*)d_in[2];
    const int* tg = (const int*)d_in[4];
    const int* sc = (const int*)d_in[5];
    float* OUT = (float*)d_out;

    // Workspace layout, total 16,385,152 B (proven safe: R7 ran with ws_size
    // >= 18,240,000; R1 proved ~24.3MB overflows and corrupts harness state):
    //   S      @ 0          : 1,280,000  (SEGN*NH fp32)
    //   A      @ 1,280,000  : 1,280,000
    //   deg    @ 2,560,000  :   320,000  (SEGN u32)
    //   cursor @ 2,880,000  :       640  (NBK u32, padded)
    //   pairs  @ 2,880,640  : 5,824,512  (NBK*CAP u32)
    //   srt    @ 8,705,152  : 7,680,000  (SEGN*SLOT u16)
    char* ws = (char*)d_ws;
    float*          S      = (float*)ws;
    float*          A      = (float*)(ws + 1280000);
    unsigned*       deg    = (unsigned*)(ws + 2560000);
    unsigned*       cursor = (unsigned*)(ws + 2880000);
    unsigned*       pairs  = (unsigned*)(ws + 2880640);
    unsigned short* srt    = (unsigned short*)(ws + 8705152);

    hipMemsetAsync(cursor, 0, NBK * sizeof(unsigned), stream);  // graph-capturable
    binA_k<<<NBLKA, 256, 0, stream>>>(tg, sc, X, As, Aa, S, A, cursor, pairs);
    binB_k<<<NBK, 1024, 0, stream>>>(cursor, pairs, srt, deg);
    gather_k<<<SEGN / 4, 256, 0, stream>>>(X, S, A, deg, srt, OUT);
}